// Round 5
// baseline (421.204 us; speedup 1.0000x reference)
//
#include <hip/hip_runtime.h>

#define B_ 4
#define S_ 2048
#define D_ 1024
#define H_ 16
#define KD_ 64
#define P_ 1024
#define M_ (B_*S_)

typedef unsigned short u16;
typedef unsigned int u32;
typedef __attribute__((ext_vector_type(4))) float f32x4;
typedef __attribute__((ext_vector_type(8))) __bf16 bf16x8;

__device__ __forceinline__ u16 f2bf(float f) {
  u32 x = __float_as_uint(f);
  return (u16)((x + 0x7fffu + ((x >> 16) & 1u)) >> 16);
}

__device__ __forceinline__ void gl_lds16(const u16* g, u16* l) {
  __builtin_amdgcn_global_load_lds((__attribute__((address_space(1))) void*)g,
                                   (__attribute__((address_space(3))) void*)l, 16, 0, 0);
}

// pack bf16(b)<<16 | bf16(a), round-to-nearest
__device__ __forceinline__ u32 pkbf(float a, float b) {
  return __builtin_amdgcn_perm(__float_as_uint(b) + 0x8000u,
                               __float_as_uint(a) + 0x8000u, 0x07060302u);
}

// ---------------- fp32 -> bf16 convert, 3 tensors in one launch ----------------
__global__ void cvt3_kernel(const float* __restrict__ q, const float* __restrict__ k,
                            const float* __restrict__ v,
                            u16* __restrict__ Xq, u16* __restrict__ Xk, u16* __restrict__ Xv) {
  const int z = blockIdx.y;
  const float* in = z == 0 ? q : z == 1 ? k : v;
  u16* out = z == 0 ? Xq : z == 1 ? Xk : Xv;
  int i = blockIdx.x * 256 + threadIdx.x;
  float4 vv = ((const float4*)in)[i];
  ((u32*)out)[i*2+0] = (u32)f2bf(vv.x) | ((u32)f2bf(vv.y) << 16);
  ((u32*)out)[i*2+1] = (u32)f2bf(vv.z) | ((u32)f2bf(vv.w) << 16);
}

// ---------------- transpose 1024x1024 fp32 -> bf16 [C][R], 4 weights ----------------
__global__ void transpose_cvt4(const float* __restrict__ Wq, const float* __restrict__ Wk,
                               const float* __restrict__ Wv, const float* __restrict__ Wo,
                               u16* __restrict__ WqT, u16* __restrict__ WkT,
                               u16* __restrict__ WvT, u16* __restrict__ WoT) {
  const int z = blockIdx.z;
  const float* in = z == 0 ? Wq : z == 1 ? Wk : z == 2 ? Wv : Wo;
  u16* out = z == 0 ? WqT : z == 1 ? WkT : z == 2 ? WvT : WoT;
  __shared__ float tile[32][33];
  int bx = blockIdx.x * 32, by = blockIdx.y * 32;
  int tx = threadIdx.x, ty = threadIdx.y; // block (32,8)
  #pragma unroll
  for (int kk = 0; kk < 4; ++kk)
    tile[ty + kk*8][tx] = in[(by + ty + kk*8) * 1024 + bx + tx];
  __syncthreads();
  #pragma unroll
  for (int kk = 0; kk < 4; ++kk)
    out[(bx + ty + kk*8) * 1024 + by + tx] = f2bf(tile[tx][ty + kk*8]);
}

// ---------------- QKV projection GEMM (batched, z selects), m97 pattern ----------------
__global__ __launch_bounds__(256) void gemm_qkv(
    const u16* __restrict__ Xq, const u16* __restrict__ Xk, const u16* __restrict__ Xv,
    const u16* __restrict__ WqT, const u16* __restrict__ WkT, const u16* __restrict__ WvT,
    const float* __restrict__ bq, const float* __restrict__ bk, const float* __restrict__ bv,
    u16* __restrict__ Qb, u16* __restrict__ Kb, u16* __restrict__ Vt)
{
  constexpr int K = 1024, N = 1024, BK = 32;
  const int z = blockIdx.z;
  const u16* A  = z == 0 ? Xq  : z == 1 ? Xk  : Xv;
  const u16* Bt = z == 0 ? WqT : z == 1 ? WkT : WvT;
  const float* bias = z == 0 ? bq : z == 1 ? bk : bv;

  __shared__ alignas(16) u16 As[128*BK];
  __shared__ alignas(16) u16 Bs[128*BK];
  const int tid = threadIdx.x;
  const int w = tid >> 6, l = tid & 63;
  const int quad = l >> 4, l16 = l & 15;
  const int wm = (w >> 1) * 64, wn = (w & 1) * 64;
  const long mBase = (long)blockIdx.x * 128;
  const int  nBase = blockIdx.y * 128;

  f32x4 acc[4][4] = {};
  const int off0 = w*1024 + l*16;

  for (int kb = 0; kb < K/BK; ++kb) {
    __syncthreads();
    #pragma unroll
    for (int p = 0; p < 2; ++p) {
      int off = p*4096 + off0;
      int row = off >> 6;
      int cb  = off & 63;
      const u16* ga = A  + (mBase + row)*K + kb*BK + (cb >> 1);
      const u16* gb = Bt + ((long)(nBase + row))*K + kb*BK + (cb >> 1);
      gl_lds16(ga, (u16*)((char*)As + p*4096 + w*1024));
      gl_lds16(gb, (u16*)((char*)Bs + p*4096 + w*1024));
    }
    __syncthreads();
    bf16x8 af[4], bf[4];
    #pragma unroll
    for (int i = 0; i < 4; ++i) af[i] = *(const bf16x8*)&As[(wm + i*16 + l16)*BK + quad*8];
    #pragma unroll
    for (int j = 0; j < 4; ++j) bf[j] = *(const bf16x8*)&Bs[(wn + j*16 + l16)*BK + quad*8];
    #pragma unroll
    for (int i = 0; i < 4; ++i)
      #pragma unroll
      for (int j = 0; j < 4; ++j)
        acc[i][j] = __builtin_amdgcn_mfma_f32_16x16x32_bf16(af[i], bf[j], acc[i][j], 0, 0, 0);
  }

  if (z < 2) {
    u16* Cout = z == 0 ? Qb : Kb;
    #pragma unroll
    for (int i = 0; i < 4; ++i)
      #pragma unroll
      for (int j = 0; j < 4; ++j)
        #pragma unroll
        for (int r = 0; r < 4; ++r) {
          long row = mBase + wm + i*16 + quad*4 + r;
          int  col = nBase + wn + j*16 + l16;
          Cout[row*N + col] = f2bf(acc[i][j][r] + bias[col]);
        }
  } else {
    // V transposed per head: Vt[(b*1024 + h*64 + d)*2048 + s]
    #pragma unroll
    for (int i = 0; i < 4; ++i)
      #pragma unroll
      for (int j = 0; j < 4; ++j) {
        int  col  = nBase + wn + j*16 + l16;       // = h*64+d
        long row0 = mBase + wm + i*16 + quad*4;    // token; +r consecutive
        int  bb = (int)(row0 >> 11);
        int  ss = (int)(row0 & 2047);
        float bcol = bias[col];
        float v0 = acc[i][j][0] + bcol, v1 = acc[i][j][1] + bcol;
        float v2 = acc[i][j][2] + bcol, v3 = acc[i][j][3] + bcol;
        uint2 pk;
        pk.x = (u32)f2bf(v0) | ((u32)f2bf(v1) << 16);
        pk.y = (u32)f2bf(v2) | ((u32)f2bf(v3) << 16);
        *(uint2*)&Vt[((long)(bb*16) * 64 + col) * 2048 + ss] = pk;
      }
  }
}

// ---------------- output projection GEMM (fp32 out) ----------------
__global__ __launch_bounds__(256) void gemm_out(const u16* __restrict__ A,
                                                const u16* __restrict__ Bt,
                                                const float* __restrict__ bias,
                                                float* __restrict__ Cout)
{
  constexpr int K = 1024, N = 1024, BK = 32;
  __shared__ alignas(16) u16 As[128*BK];
  __shared__ alignas(16) u16 Bs[128*BK];
  const int tid = threadIdx.x;
  const int w = tid >> 6, l = tid & 63;
  const int quad = l >> 4, l16 = l & 15;
  const int wm = (w >> 1) * 64, wn = (w & 1) * 64;
  const long mBase = (long)blockIdx.x * 128;
  const int  nBase = blockIdx.y * 128;

  f32x4 acc[4][4] = {};
  const int off0 = w*1024 + l*16;

  for (int kb = 0; kb < K/BK; ++kb) {
    __syncthreads();
    #pragma unroll
    for (int p = 0; p < 2; ++p) {
      int off = p*4096 + off0;
      int row = off >> 6;
      int cb  = off & 63;
      const u16* ga = A  + (mBase + row)*K + kb*BK + (cb >> 1);
      const u16* gb = Bt + ((long)(nBase + row))*K + kb*BK + (cb >> 1);
      gl_lds16(ga, (u16*)((char*)As + p*4096 + w*1024));
      gl_lds16(gb, (u16*)((char*)Bs + p*4096 + w*1024));
    }
    __syncthreads();
    bf16x8 af[4], bf[4];
    #pragma unroll
    for (int i = 0; i < 4; ++i) af[i] = *(const bf16x8*)&As[(wm + i*16 + l16)*BK + quad*8];
    #pragma unroll
    for (int j = 0; j < 4; ++j) bf[j] = *(const bf16x8*)&Bs[(wn + j*16 + l16)*BK + quad*8];
    #pragma unroll
    for (int i = 0; i < 4; ++i)
      #pragma unroll
      for (int j = 0; j < 4; ++j)
        acc[i][j] = __builtin_amdgcn_mfma_f32_16x16x32_bf16(af[i], bf[j], acc[i][j], 0, 0, 0);
  }

  #pragma unroll
  for (int i = 0; i < 4; ++i)
    #pragma unroll
    for (int j = 0; j < 4; ++j)
      #pragma unroll
      for (int r = 0; r < 4; ++r) {
        long row = mBase + wm + i*16 + quad*4 + r;
        int  col = nBase + wn + j*16 + l16;
        Cout[row*N + col] = acc[i][j][r] + bias[col];
      }
}

// ---------------- flash attention core: one 32-row q-subtile over [kt0,ktN) + diag ----
// Static-shift softmax (exponent = c1*s - sl2*k): partials over disjoint kt ranges ADD,
// enabling exact split-K load balancing across waves.
#define PST 136
__device__ __forceinline__ void attn_tiles(
    const u16* __restrict__ Qp, const u16* __restrict__ Kp, const u16* __restrict__ Vp,
    int kt0, int ktN, int qt, bool dodiag, int w, int l16, int quad,
    float sl2, float c1, u16 (*Ps)[16][PST], f32x4 (&o)[2][4], float (&lsum)[2])
{
  const float rs1 = sl2, rs2 = 2.f*sl2, rs3 = 3.f*sl2;
  bf16x8 qf[2][2];
  #pragma unroll
  for (int i = 0; i < 2; ++i)
    #pragma unroll
    for (int kk = 0; kk < 2; ++kk)
      qf[i][kk] = *(const bf16x8*)&Qp[(long)(i*16 + l16)*P_ + kk*32 + quad*8];
  #pragma unroll
  for (int i = 0; i < 2; ++i) {
    lsum[i] = 0.f;
    #pragma unroll
    for (int jn = 0; jn < 4; ++jn) o[i][jn] = (f32x4){0.f, 0.f, 0.f, 0.f};
  }

  for (int kt = kt0; kt < ktN; ++kt) {
    const u16* kts = Kp + (long)(kt*128 + l16)*P_;
    #pragma unroll
    for (int jh = 0; jh < 2; ++jh) {
      f32x4 st[2][4];
      #pragma unroll
      for (int jj = 0; jj < 4; ++jj) {
        const int j = jh*4 + jj;
        const u16* kp = kts + (long)(j*16)*P_;
        bf16x8 kf0 = *(const bf16x8*)(kp + quad*8);
        bf16x8 kf1 = *(const bf16x8*)(kp + 32 + quad*8);
        #pragma unroll
        for (int i = 0; i < 2; ++i) {
          f32x4 t = {};
          t = __builtin_amdgcn_mfma_f32_16x16x32_bf16(kf0, qf[i][0], t, 0, 0, 0);
          t = __builtin_amdgcn_mfma_f32_16x16x32_bf16(kf1, qf[i][1], t, 0, 0, 0);
          st[i][jj] = t;
        }
      }
      #pragma unroll
      for (int i = 0; i < 2; ++i)
        #pragma unroll
        for (int jj = 0; jj < 4; ++jj) {
          const int j = jh*4 + jj;
          const float kb  = (float)(kt*128 + j*16 + quad*4);
          const float bij = -sl2 * kb;
          float p0 = __builtin_amdgcn_exp2f(fmaf(st[i][jj][0], c1, bij));
          float p1 = __builtin_amdgcn_exp2f(fmaf(st[i][jj][1], c1, bij) - rs1);
          float p2 = __builtin_amdgcn_exp2f(fmaf(st[i][jj][2], c1, bij) - rs2);
          float p3 = __builtin_amdgcn_exp2f(fmaf(st[i][jj][3], c1, bij) - rs3);
          lsum[i] += (p0 + p1) + (p2 + p3);
          uint2 pk; pk.x = pkbf(p0, p1); pk.y = pkbf(p2, p3);
          *(uint2*)&Ps[i][l16][j*16 + quad*4] = pk;
        }
    }
    #pragma unroll
    for (int ks = 0; ks < 4; ++ks) {
      bf16x8 pb0 = *(const bf16x8*)&Ps[0][l16][ks*32 + quad*8];
      bf16x8 pb1 = *(const bf16x8*)&Ps[1][l16][ks*32 + quad*8];
      #pragma unroll
      for (int jn = 0; jn < 4; ++jn) {
        bf16x8 vf = *(const bf16x8*)&Vp[(long)(jn*16 + l16)*S_ + kt*128 + ks*32 + quad*8];
        o[0][jn] = __builtin_amdgcn_mfma_f32_16x16x32_bf16(vf, pb0, o[0][jn], 0, 0, 0);
        o[1][jn] = __builtin_amdgcn_mfma_f32_16x16x32_bf16(vf, pb1, o[1][jn], 0, 0, 0);
      }
    }
  }

  if (dodiag) {
    const int kt = qt;
    const int jmax = 2*w + 2, ksmax = w + 1;
    const u16* kts = Kp + (long)(kt*128 + l16)*P_;
    for (int j = 0; j < jmax; ++j) {
      const u16* kp = kts + (long)(j*16)*P_;
      bf16x8 kf0 = *(const bf16x8*)(kp + quad*8);
      bf16x8 kf1 = *(const bf16x8*)(kp + 32 + quad*8);
      const int kl0 = j*16 + quad*4;
      const float kb  = (float)(kt*128 + kl0);
      #pragma unroll
      for (int i = 0; i < 2; ++i) {
        f32x4 t = {};
        t = __builtin_amdgcn_mfma_f32_16x16x32_bf16(kf0, qf[i][0], t, 0, 0, 0);
        t = __builtin_amdgcn_mfma_f32_16x16x32_bf16(kf1, qf[i][1], t, 0, 0, 0);
        const int ql = w*32 + i*16 + l16;
        const float bij = -sl2 * kb;
        float x0 = fmaf(t[0], c1, bij);
        float x1 = fmaf(t[1], c1, bij) - rs1;
        float x2 = fmaf(t[2], c1, bij) - rs2;
        float x3 = fmaf(t[3], c1, bij) - rs3;
        if (kl0 + 0 > ql) x0 = -1e30f;
        if (kl0 + 1 > ql) x1 = -1e30f;
        if (kl0 + 2 > ql) x2 = -1e30f;
        if (kl0 + 3 > ql) x3 = -1e30f;
        float p0 = __builtin_amdgcn_exp2f(x0);
        float p1 = __builtin_amdgcn_exp2f(x1);
        float p2 = __builtin_amdgcn_exp2f(x2);
        float p3 = __builtin_amdgcn_exp2f(x3);
        lsum[i] += (p0 + p1) + (p2 + p3);
        uint2 pk; pk.x = pkbf(p0, p1); pk.y = pkbf(p2, p3);
        *(uint2*)&Ps[i][l16][j*16 + quad*4] = pk;
      }
    }
    for (int ks = 0; ks < ksmax; ++ks) {
      bf16x8 pb0 = *(const bf16x8*)&Ps[0][l16][ks*32 + quad*8];
      bf16x8 pb1 = *(const bf16x8*)&Ps[1][l16][ks*32 + quad*8];
      #pragma unroll
      for (int jn = 0; jn < 4; ++jn) {
        bf16x8 vf = *(const bf16x8*)&Vp[(long)(jn*16 + l16)*S_ + kt*128 + ks*32 + quad*8];
        o[0][jn] = __builtin_amdgcn_mfma_f32_16x16x32_bf16(vf, pb0, o[0][jn], 0, 0, 0);
        o[1][jn] = __builtin_amdgcn_mfma_f32_16x16x32_bf16(vf, pb1, o[1][jn], 0, 0, 0);
      }
    }
  }
}

// ---------------- attention: split-K pair-balanced, 4096 one-wave blocks ----------------
// pair p: qt_hi = 15-p (p<8), qt_lo = p. Wave A: qt_hi kt 0..7 -> partial.
// Wave B: qt_hi kt 8..diag -> partial; then qt_lo full -> direct store.
// Every wave does 8-9 key-tiles: balanced makespan with all 4096 waves co-resident.
__global__ __launch_bounds__(64, 4) void attn_kernel(const u16* __restrict__ Qb,
                                                     const u16* __restrict__ Kb,
                                                     const u16* __restrict__ Vt,
                                                     u16* __restrict__ Ob,
                                                     float* __restrict__ Part)
{
  __shared__ alignas(16) u16 Ps[2][16][PST];
  const int n = blockIdx.x;
  const int p  = n >> 9;            // 0..7
  const int ab = (n >> 8) & 1;      // 0 = A, 1 = B
  const int r8 = n & 255;
  const int b = r8 >> 6, h = (r8 >> 2) & 15, w = r8 & 3;
  const int qt_hi = 15 - p, qt_lo = p;
  const int l = threadIdx.x;
  const int quad = l >> 4, l16 = l & 15;
  const float LOG2E = 1.44269504089f;
  const float slope = exp2f(-0.5f * (float)(h + 1));
  const float c1  = 0.125f * LOG2E;
  const float sl2 = slope * LOG2E;

  const u16* Kp = Kb + ((long)(b*S_))*P_ + h*KD_;
  const u16* Vp = Vt + ((long)(b*H_ + h))*KD_*S_;
  const int slot = ((p*4 + w)*4 + b)*16 + h;

  f32x4 o[2][4];
  float lsum[2];

  if (ab == 0) {
    const int q0 = qt_hi*128 + w*32;
    attn_tiles(Qb + ((long)(b*S_ + q0))*P_ + h*KD_, Kp, Vp,
               0, 8, qt_hi, false, w, l16, quad, sl2, c1, Ps, o, lsum);
    float* dst = Part + ((long)slot*64 + l)*36;
    #pragma unroll
    for (int i = 0; i < 2; ++i)
      #pragma unroll
      for (int jn = 0; jn < 4; ++jn)
        *(f32x4*)(dst + i*16 + jn*4) = o[i][jn];
    dst[32] = lsum[0]; dst[33] = lsum[1];
  } else {
    const int q0 = qt_hi*128 + w*32;
    attn_tiles(Qb + ((long)(b*S_ + q0))*P_ + h*KD_, Kp, Vp,
               8, qt_hi, qt_hi, true, w, l16, quad, sl2, c1, Ps, o, lsum);
    float* dst = Part + ((long)(2048 + slot)*64 + l)*36;
    #pragma unroll
    for (int i = 0; i < 2; ++i)
      #pragma unroll
      for (int jn = 0; jn < 4; ++jn)
        *(f32x4*)(dst + i*16 + jn*4) = o[i][jn];
    dst[32] = lsum[0]; dst[33] = lsum[1];

    // phase 2: qt_lo handled fully -> direct epilogue
    const int q0b = qt_lo*128 + w*32;
    attn_tiles(Qb + ((long)(b*S_ + q0b))*P_ + h*KD_, Kp, Vp,
               0, qt_lo, qt_lo, true, w, l16, quad, sl2, c1, Ps, o, lsum);
    #pragma unroll
    for (int i = 0; i < 2; ++i) {
      float ls = lsum[i];
      ls += __shfl_xor(ls, 16, 64);
      ls += __shfl_xor(ls, 32, 64);
      const float inv = 1.0f / ls;
      #pragma unroll
      for (int jn = 0; jn < 4; ++jn) {
        float v0 = o[i][jn][0] * inv, v1 = o[i][jn][1] * inv;
        float v2 = o[i][jn][2] * inv, v3 = o[i][jn][3] * inv;
        uint2 pk;
        pk.x = (u32)f2bf(v0) | ((u32)f2bf(v1) << 16);
        pk.y = (u32)f2bf(v2) | ((u32)f2bf(v3) << 16);
        *(uint2*)&Ob[((long)(b*S_ + q0b + i*16 + l16))*P_ + h*KD_ + jn*16 + quad*4] = pk;
      }
    }
  }
}

// ---------------- combine split-K partials for qt_hi subtiles ----------------
__global__ __launch_bounds__(64) void combine_kernel(const float* __restrict__ Part,
                                                     u16* __restrict__ Ob)
{
  const int sid = blockIdx.x;           // 0..2047
  const int l = threadIdx.x;
  const int h = sid & 15, b = (sid >> 4) & 3, w = (sid >> 6) & 3, p = sid >> 8;
  const int qt = 15 - p;
  const int q0 = qt*128 + w*32;
  const int quad = l >> 4, l16 = l & 15;
  const float* A  = Part + ((long)sid*64 + l)*36;
  const float* Bp = Part + ((long)(2048 + sid)*64 + l)*36;

  f32x4 o[2][4];
  float ls[2];
  #pragma unroll
  for (int i = 0; i < 2; ++i) {
    ls[i] = A[32 + i] + Bp[32 + i];
    #pragma unroll
    for (int jn = 0; jn < 4; ++jn)
      o[i][jn] = *(const f32x4*)(A + i*16 + jn*4) + *(const f32x4*)(Bp + i*16 + jn*4);
  }
  #pragma unroll
  for (int i = 0; i < 2; ++i) {
    float s = ls[i];
    s += __shfl_xor(s, 16, 64);
    s += __shfl_xor(s, 32, 64);
    const float inv = 1.0f / s;
    #pragma unroll
    for (int jn = 0; jn < 4; ++jn) {
      float v0 = o[i][jn][0] * inv, v1 = o[i][jn][1] * inv;
      float v2 = o[i][jn][2] * inv, v3 = o[i][jn][3] * inv;
      uint2 pk;
      pk.x = (u32)f2bf(v0) | ((u32)f2bf(v1) << 16);
      pk.y = (u32)f2bf(v2) | ((u32)f2bf(v3) << 16);
      *(uint2*)&Ob[((long)(b*S_ + q0 + i*16 + l16))*P_ + h*KD_ + jn*16 + quad*4] = pk;
    }
  }
}

extern "C" void kernel_launch(void* const* d_in, const int* in_sizes, int n_in,
                              void* d_out, int out_size, void* d_ws, size_t ws_size,
                              hipStream_t stream) {
  const float* q  = (const float*)d_in[0];
  const float* k  = (const float*)d_in[1];
  const float* v  = (const float*)d_in[2];
  const float* Wq = (const float*)d_in[3];
  const float* bq = (const float*)d_in[4];
  const float* Wk = (const float*)d_in[5];
  const float* bk = (const float*)d_in[6];
  const float* Wv = (const float*)d_in[7];
  const float* bv = (const float*)d_in[8];
  const float* Wo = (const float*)d_in[9];
  const float* bo = (const float*)d_in[10];

  const size_t X_ELEMS = (size_t)M_ * P_;
  const size_t W_ELEMS = (size_t)D_ * P_;
  u16* ws  = (u16*)d_ws;
  u16* Xq  = ws;
  u16* Xk  = Xq  + X_ELEMS;
  u16* Xv  = Xk  + X_ELEMS;
  u16* WqT = Xv  + X_ELEMS;
  u16* WkT = WqT + W_ELEMS;
  u16* WvT = WkT + W_ELEMS;
  u16* WoT = WvT + W_ELEMS;
  u16* Qb  = WoT + W_ELEMS;
  u16* Kb  = Qb  + X_ELEMS;
  u16* Vt  = Kb  + X_ELEMS;      // transposed V: [b][h][d][s]
  u16* Attn = Xq;                // reuse: Xq dead after projections
  // split-K partials: 4096 slots x 64 lanes x 36 f32 = 37.75 MB, overlaid on
  // Xk..WvT (38 MB, all dead after gemm_qkv). WoT stays live for gemm_out.
  float* Part = (float*)Xk;

  cvt3_kernel<<<dim3((unsigned)(X_ELEMS/4/256), 3), 256, 0, stream>>>(q, k, v, Xq, Xk, Xv);

  transpose_cvt4<<<dim3(32, 32, 4), dim3(32, 8), 0, stream>>>(Wq, Wk, Wv, Wo,
                                                              WqT, WkT, WvT, WoT);

  gemm_qkv<<<dim3(M_/128, P_/128, 3), 256, 0, stream>>>(Xq, Xk, Xv, WqT, WkT, WvT,
                                                        bq, bk, bv, Qb, Kb, Vt);

  attn_kernel<<<dim3(4096), 64, 0, stream>>>(Qb, Kb, Vt, Attn, Part);
  combine_kernel<<<dim3(2048), 64, 0, stream>>>(Part, Attn);

  gemm_out<<<dim3(M_/128, P_/128), 256, 0, stream>>>(Attn, WoT, bo, (float*)d_out);
}